// Round 5
// baseline (223.827 us; speedup 1.0000x reference)
//
#include <hip/hip_runtime.h>

typedef long long i64;
typedef __attribute__((ext_vector_type(8))) short short8;
typedef __attribute__((ext_vector_type(4))) unsigned short us4;
typedef __attribute__((ext_vector_type(4))) float f32x4;

__device__ __forceinline__ unsigned short bf16_rtn(float x) {
  unsigned u = __float_as_uint(x);
  unsigned r = (u + 0x7FFFu + ((u >> 16) & 1u)) >> 16;
  return (unsigned short)r;
}
__device__ __forceinline__ float bf16_to_f(unsigned short h) {
  return __uint_as_float(((unsigned)h) << 16);
}

// ---------------------------------------------------------------------------
// init: zero counts[N] and nz (replaces two hipMemsetAsync dispatches)
// ---------------------------------------------------------------------------
__global__ void init_kernel(int* __restrict__ counts, int N, int* __restrict__ nz) {
  int i = blockIdx.x * blockDim.x + threadIdx.x;
  if (i < N) counts[i] = 0;
  if (i == 0) nz[0] = 0;
}

// Edge dtype detection: int64 storage => every odd int32 word of row 0 is 0.
// nz != 0 => int32 storage.
__global__ void detect64_kernel(const int* __restrict__ ei32, int E, int* __restrict__ nz) {
  int i = blockIdx.x * blockDim.x + threadIdx.x;   // 0..65535
  i64 idx = (i64)i * E / 65536;
  if (ei32[2 * idx + 1] != 0) nz[0] = 1;           // benign race
}

__device__ __forceinline__ int edge_at(const int* __restrict__ ei32, int is64, i64 elem) {
  return is64 ? ei32[2 * elem] : ei32[(int)elem];
}

__global__ void count_kernel(const int* __restrict__ ei32, const int* __restrict__ nz,
                             int* __restrict__ counts, int E) {
  int e = blockIdx.x * blockDim.x + threadIdx.x;
  if (e >= E) return;
  int is64 = (nz[0] == 0);
  int d = edge_at(ei32, is64, (i64)E + e);
  atomicAdd(&counts[d], 1);
}

// ---------------------------------------------------------------------------
// Device-wide exclusive scan of counts (3 phases, 1024 elems per block).
// ---------------------------------------------------------------------------
__global__ __launch_bounds__(256) void psum_kernel(const int* __restrict__ counts,
                                                   int* __restrict__ bsum, int N) {
  int base = blockIdx.x * 1024 + threadIdx.x * 4;
  int s = 0;
#pragma unroll
  for (int j = 0; j < 4; ++j) {
    int i = base + j;
    if (i < N) s += counts[i];
  }
#pragma unroll
  for (int off = 32; off > 0; off >>= 1) s += __shfl_down(s, off);
  __shared__ int ws[4];
  int wid = threadIdx.x >> 6;
  if ((threadIdx.x & 63) == 0) ws[wid] = s;
  __syncthreads();
  if (threadIdx.x == 0) bsum[blockIdx.x] = ws[0] + ws[1] + ws[2] + ws[3];
}

__global__ __launch_bounds__(1024) void bscan_kernel(int* __restrict__ bsum, int nb,
                                                     int* __restrict__ offs_last, int E) {
  __shared__ int sh[1024];
  int tid = threadIdx.x;
  int v = (tid < nb) ? bsum[tid] : 0;
  sh[tid] = v;
  __syncthreads();
  for (int off = 1; off < 1024; off <<= 1) {
    int t = (tid >= off) ? sh[tid - off] : 0;
    __syncthreads();
    sh[tid] += t;
    __syncthreads();
  }
  if (tid < nb) bsum[tid] = sh[tid] - v;  // exclusive
  if (tid == 0) offs_last[0] = E;
}

__global__ __launch_bounds__(256) void scatter_kernel(
    const int* __restrict__ counts, const int* __restrict__ bsum,
    int* __restrict__ offs, int* __restrict__ cursor, float* __restrict__ dinv, int N) {
  __shared__ int wsum[4];
  int tid = threadIdx.x;
  int base = blockIdx.x * 1024 + tid * 4;
  int c[4];
  int s = 0;
#pragma unroll
  for (int j = 0; j < 4; ++j) {
    int i = base + j;
    c[j] = (i < N) ? counts[i] : 0;
    s += c[j];
  }
  int lane = tid & 63, wid = tid >> 6;
  int incl = s;
#pragma unroll
  for (int off = 1; off < 64; off <<= 1) {
    int t = __shfl_up(incl, off);
    if (lane >= off) incl += t;
  }
  if (lane == 63) wsum[wid] = incl;
  __syncthreads();
  int wo = 0;
  for (int wq = 0; wq < wid; ++wq) wo += wsum[wq];
  int excl = incl - s + wo + bsum[blockIdx.x];
#pragma unroll
  for (int j = 0; j < 4; ++j) {
    int i = base + j;
    if (i < N) {
      offs[i] = excl;
      cursor[i] = excl;
      dinv[i] = rsqrtf((float)c[j] + 1.0f);
      excl += c[j];
    }
  }
}

__global__ void fill_kernel(const int* __restrict__ ei32, const int* __restrict__ nz,
                            int* __restrict__ cursor, int* __restrict__ col, int E) {
  int e = blockIdx.x * blockDim.x + threadIdx.x;
  if (e >= E) return;
  int is64 = (nz[0] == 0);
  int s = edge_at(ei32, is64, e);
  int d = edge_at(ei32, is64, (i64)E + e);
  int pos = atomicAdd(&cursor[d], 1);
  col[pos] = s;
}

// ---------------------------------------------------------------------------
// Weight split+transpose for all 3 weights in one launch (192 blocks).
// W[128][128] fp32 -> WT hi/lo bf16 [c][k], W = hi + lo to ~2^-18 relative.
// ---------------------------------------------------------------------------
__global__ __launch_bounds__(256) void wsplit_kernel(
    const float* __restrict__ Wa, unsigned short* __restrict__ wha, unsigned short* __restrict__ wla,
    const float* __restrict__ Wb, unsigned short* __restrict__ whb, unsigned short* __restrict__ wlb,
    const float* __restrict__ Wc, unsigned short* __restrict__ whc, unsigned short* __restrict__ wlc) {
  int b = blockIdx.x >> 6;                  // 0..2 : which weight
  int t = (blockIdx.x & 63) * 256 + threadIdx.x;  // 0..16383
  const float* W = (b == 0) ? Wa : (b == 1) ? Wb : Wc;
  unsigned short* wh = (b == 0) ? wha : (b == 1) ? whb : whc;
  unsigned short* wl = (b == 0) ? wla : (b == 1) ? wlb : wlc;
  int c = t >> 7, k = t & 127;
  float w = W[k * 128 + c];
  unsigned short hi = bf16_rtn(w);
  unsigned short lo = bf16_rtn(w - bf16_to_f(hi));
  wh[c * 128 + k] = hi;
  wl[c * 128 + k] = lo;
}

// ---------------------------------------------------------------------------
// LDS-free split-bf16 MFMA GEMM: C[N,128] = A[N,128] @ W[128,128].
// A,W split hi+lo bf16, 3 MFMA passes (hh, lh, hl) -> ~fp32 accuracy.
// Each wave owns 32 rows x 128 cols; A fragments loaded straight from global
// (2x float4/lane, split in registers), B^T fragments straight from L2
// (16B/lane us8). No LDS, no __syncthreads -> free pipelining.
// MODE 0: out = bf16( acc * dinv[row] )    MODE 1: out = relu(acc + bias[col])
// ---------------------------------------------------------------------------
template <int MODE>
__global__ __launch_bounds__(256, 4) void gemm_mfma(
    const float* __restrict__ A, const unsigned short* __restrict__ WhT,
    const unsigned short* __restrict__ WlT, const float* __restrict__ aux,
    void* __restrict__ outv, int N) {
  int tid = threadIdx.x;
  int wid = tid >> 6, lane = tid & 63;
  int lr = lane & 15, kg = (lane >> 4) * 8;   // k-offset of this lane's fragment
  int rowbase = blockIdx.x * 128 + wid * 32;

  f32x4 acc[2][8];
#pragma unroll
  for (int tr = 0; tr < 2; ++tr)
#pragma unroll
    for (int tc = 0; tc < 8; ++tc) acc[tr][tc] = (f32x4){0.f, 0.f, 0.f, 0.f};

  int r[2] = {rowbase + lr, rowbase + 16 + lr};

  for (int kc = 0; kc < 128; kc += 32) {
    int k0 = kc + kg;
    short8 afh[2], afl[2];
#pragma unroll
    for (int tr = 0; tr < 2; ++tr) {
      float4 va = make_float4(0.f, 0.f, 0.f, 0.f), vb = va;
      if (r[tr] < N) {
        const float* p = &A[(i64)r[tr] * 128 + k0];
        va = *reinterpret_cast<const float4*>(p);
        vb = *reinterpret_cast<const float4*>(p + 4);
      }
      float xs[8] = {va.x, va.y, va.z, va.w, vb.x, vb.y, vb.z, vb.w};
#pragma unroll
      for (int j = 0; j < 8; ++j) {
        unsigned short h = bf16_rtn(xs[j]);
        afh[tr][j] = (short)h;
        afl[tr][j] = (short)bf16_rtn(xs[j] - bf16_to_f(h));
      }
    }
#pragma unroll
    for (int tc = 0; tc < 8; ++tc) {
      int c = tc * 16 + lr;
      short8 bfh = *reinterpret_cast<const short8*>(&WhT[c * 128 + k0]);
      short8 bfl = *reinterpret_cast<const short8*>(&WlT[c * 128 + k0]);
#pragma unroll
      for (int tr = 0; tr < 2; ++tr) {
        acc[tr][tc] = __builtin_amdgcn_mfma_f32_16x16x32_bf16(afh[tr], bfh, acc[tr][tc], 0, 0, 0);
        acc[tr][tc] = __builtin_amdgcn_mfma_f32_16x16x32_bf16(afl[tr], bfh, acc[tr][tc], 0, 0, 0);
        acc[tr][tc] = __builtin_amdgcn_mfma_f32_16x16x32_bf16(afh[tr], bfl, acc[tr][tc], 0, 0, 0);
      }
    }
  }

  // epilogue (C/D layout: col = tc*16 + (lane&15), row = tr*16 + (lane>>4)*4 + reg)
  if (MODE == 0) {
    unsigned short* hb = (unsigned short*)outv;
#pragma unroll
    for (int tr = 0; tr < 2; ++tr) {
#pragma unroll
      for (int reg = 0; reg < 4; ++reg) {
        int row = rowbase + tr * 16 + (lane >> 4) * 4 + reg;
        if (row >= N) continue;
        float dv = aux[row];
#pragma unroll
        for (int tc = 0; tc < 8; ++tc) {
          int colg = tc * 16 + lr;
          hb[(i64)row * 128 + colg] = bf16_rtn(acc[tr][tc][reg] * dv);
        }
      }
    }
  } else {
    float* out = (float*)outv;
#pragma unroll
    for (int tr = 0; tr < 2; ++tr) {
#pragma unroll
      for (int reg = 0; reg < 4; ++reg) {
        int row = rowbase + tr * 16 + (lane >> 4) * 4 + reg;
        if (row >= N) continue;
#pragma unroll
        for (int tc = 0; tc < 8; ++tc) {
          int colg = tc * 16 + lr;
          out[(i64)row * 128 + colg] = fmaxf(acc[tr][tc][reg] + aux[colg], 0.f);
        }
      }
    }
  }
}

// ---------------------------------------------------------------------------
// Aggregation over bf16 H': out[v] = (relu?)( dinv[v]*(H'[v] + sum_s H'[s]) + b )
// Half-wave (32 lanes) per node, lane = 4 channels (8B us4), unroll 4 for MLP.
// fp32 accumulate, fp32 output.
// ---------------------------------------------------------------------------
template <int RELU>
__global__ __launch_bounds__(256) void agg_bf16(
    const unsigned short* __restrict__ hb, const int* __restrict__ col,
    const int* __restrict__ offs, const float* __restrict__ dinv,
    const float* __restrict__ bias, float* __restrict__ out, int N) {
  i64 gt = (i64)blockIdx.x * blockDim.x + threadIdx.x;
  int gw = (int)(gt >> 6);
  int lane = threadIdx.x & 63;
  int v = gw * 2 + (lane >> 5);
  if (v >= N) return;
  int ch = (lane & 31) * 4;
  us4 sv = *reinterpret_cast<const us4*>(&hb[(i64)v * 128 + ch]);
  float a0 = bf16_to_f(sv[0]), a1 = bf16_to_f(sv[1]);
  float a2 = bf16_to_f(sv[2]), a3 = bf16_to_f(sv[3]);
  int beg = offs[v], end = offs[v + 1];
  int i = beg;
  for (; i + 3 < end; i += 4) {
    int s0 = col[i], s1 = col[i + 1], s2 = col[i + 2], s3 = col[i + 3];
    us4 u0 = *reinterpret_cast<const us4*>(&hb[(i64)s0 * 128 + ch]);
    us4 u1 = *reinterpret_cast<const us4*>(&hb[(i64)s1 * 128 + ch]);
    us4 u2 = *reinterpret_cast<const us4*>(&hb[(i64)s2 * 128 + ch]);
    us4 u3 = *reinterpret_cast<const us4*>(&hb[(i64)s3 * 128 + ch]);
    a0 += (bf16_to_f(u0[0]) + bf16_to_f(u1[0])) + (bf16_to_f(u2[0]) + bf16_to_f(u3[0]));
    a1 += (bf16_to_f(u0[1]) + bf16_to_f(u1[1])) + (bf16_to_f(u2[1]) + bf16_to_f(u3[1]));
    a2 += (bf16_to_f(u0[2]) + bf16_to_f(u1[2])) + (bf16_to_f(u2[2]) + bf16_to_f(u3[2]));
    a3 += (bf16_to_f(u0[3]) + bf16_to_f(u1[3])) + (bf16_to_f(u2[3]) + bf16_to_f(u3[3]));
  }
  for (; i < end; ++i) {
    int s0 = col[i];
    us4 u0 = *reinterpret_cast<const us4*>(&hb[(i64)s0 * 128 + ch]);
    a0 += bf16_to_f(u0[0]); a1 += bf16_to_f(u0[1]);
    a2 += bf16_to_f(u0[2]); a3 += bf16_to_f(u0[3]);
  }
  float dv = dinv[v];
  float4 b = *reinterpret_cast<const float4*>(&bias[ch]);
  float4 rr;
  rr.x = fmaf(a0, dv, b.x);
  rr.y = fmaf(a1, dv, b.y);
  rr.z = fmaf(a2, dv, b.z);
  rr.w = fmaf(a3, dv, b.w);
  if (RELU) {
    rr.x = fmaxf(rr.x, 0.f); rr.y = fmaxf(rr.y, 0.f);
    rr.z = fmaxf(rr.z, 0.f); rr.w = fmaxf(rr.w, 0.f);
  }
  *reinterpret_cast<float4*>(&out[(i64)v * 128 + ch]) = rr;
}

// ---------------------------------------------------------------------------
extern "C" void kernel_launch(void* const* d_in, const int* in_sizes, int n_in,
                              void* d_out, int out_size, void* d_ws, size_t ws_size,
                              hipStream_t stream) {
  const float* x  = (const float*)d_in[0];
  const int*   ei = (const int*)d_in[1];
  const float* W1 = (const float*)d_in[2];
  const float* b1 = (const float*)d_in[3];
  const float* W2 = (const float*)d_in[4];
  const float* b2 = (const float*)d_in[5];
  const float* Wd = (const float*)d_in[6];
  const float* bd = (const float*)d_in[7];
  int N = in_sizes[0] / 128;
  int E = in_sizes[1] / 2;
  float* out = (float*)d_out;

  // workspace layout
  char* w = (char*)d_ws;
  float*          z    = (float*)w;                        // N*128 fp32
  unsigned short* wh1  = (unsigned short*)(z + (i64)N * 128);
  unsigned short* wl1  = wh1 + 16384;
  unsigned short* wh2  = wl1 + 16384;
  unsigned short* wl2  = wh2 + 16384;
  unsigned short* whd  = wl2 + 16384;
  unsigned short* wld  = whd + 16384;
  int*   counts = (int*)(wld + 16384);
  int*   offs   = counts + N;                              // N+1
  int*   cursor = offs + N + 1;                            // N
  int*   col    = cursor + N;                              // E
  float* dinv   = (float*)(col + E);                       // N
  int*   nz     = (int*)(dinv + N);                        // 1
  int*   bsum   = nz + 1;                                  // <=1024
  unsigned short* hb = (unsigned short*)d_out;  // bf16 H' scratch; overwritten by decoder

  int nb = (N + 1023) / 1024;

  init_kernel<<<(N + 255) / 256, 256, 0, stream>>>(counts, N, nz);
  detect64_kernel<<<256, 256, 0, stream>>>(ei, E, nz);
  count_kernel<<<(E + 255) / 256, 256, 0, stream>>>(ei, nz, counts, E);
  psum_kernel<<<nb, 256, 0, stream>>>(counts, bsum, N);
  bscan_kernel<<<1, 1024, 0, stream>>>(bsum, nb, offs + N, E);
  scatter_kernel<<<nb, 256, 0, stream>>>(counts, bsum, offs, cursor, dinv, N);
  fill_kernel<<<(E + 255) / 256, 256, 0, stream>>>(ei, nz, cursor, col, E);
  wsplit_kernel<<<192, 256, 0, stream>>>(W1, wh1, wl1, W2, wh2, wl2, Wd, whd, wld);

  int gblocks = (N + 127) / 128;
  i64 aggthreads = (i64)((N + 1) / 2) * 64;
  int ablocks = (int)((aggthreads + 255) / 256);

  // conv1: hb = bf16((x@W1)*dinv) ; z = relu(dinv*(hb_v + sum) + b1)
  gemm_mfma<0><<<gblocks, 256, 0, stream>>>(x, wh1, wl1, dinv, hb, N);
  agg_bf16<1><<<ablocks, 256, 0, stream>>>(hb, col, offs, dinv, b1, z, N);
  // conv2: hb = bf16((z@W2)*dinv) ; z = dinv*(hb_v + sum) + b2 (no relu)
  gemm_mfma<0><<<gblocks, 256, 0, stream>>>(z, wh2, wl2, dinv, hb, N);
  agg_bf16<0><<<ablocks, 256, 0, stream>>>(hb, col, offs, dinv, b2, z, N);
  // decoder: out = relu(z @ Wd + bd)
  gemm_mfma<1><<<gblocks, 256, 0, stream>>>(z, whd, wld, bd, out, N);
}

// Round 6
// 218.382 us; speedup vs baseline: 1.0249x; 1.0249x over previous
//
#include <hip/hip_runtime.h>

typedef long long i64;
typedef __attribute__((ext_vector_type(8))) short short8;
typedef __attribute__((ext_vector_type(4))) unsigned short us4;
typedef __attribute__((ext_vector_type(4))) float f32x4;

__device__ __forceinline__ unsigned short bf16_rtn(float x) {
  unsigned u = __float_as_uint(x);
  unsigned r = (u + 0x7FFFu + ((u >> 16) & 1u)) >> 16;
  return (unsigned short)r;
}
__device__ __forceinline__ float bf16_to_f(unsigned short h) {
  return __uint_as_float(((unsigned)h) << 16);
}

// ---------------------------------------------------------------------------
// Per-wave edge-dtype detection: sample the odd int32 word of 64 src elements
// (int64 storage + values < 2^31 => all zero). For int32 data those words are
// edge values: P(all 64 == 0) ~ (1/N)^64 ~ 0, and deterministic per replay.
// Returns wave-uniform true => int64 storage.
// ---------------------------------------------------------------------------
__device__ __forceinline__ bool wave_is64(const int* __restrict__ ei32, int E, int e0) {
  int probe = ei32[2 * (i64)e0 + 1];
  return __ballot(probe != 0) == 0ULL;
}

// ---------------------------------------------------------------------------
// init: zero counts[N]  +  weight split/transpose for all 3 weights.
// Blocks [0, nbInit) zero counts; blocks [nbInit, nbInit+192) split weights:
// W[128][128] fp32 -> WT hi/lo bf16 [c][k], W = hi + lo to ~2^-18 relative.
// ---------------------------------------------------------------------------
__global__ __launch_bounds__(256) void init_split_kernel(
    int* __restrict__ counts, int N,
    const float* __restrict__ Wa, unsigned short* __restrict__ wha, unsigned short* __restrict__ wla,
    const float* __restrict__ Wb, unsigned short* __restrict__ whb, unsigned short* __restrict__ wlb,
    const float* __restrict__ Wc, unsigned short* __restrict__ whc, unsigned short* __restrict__ wlc) {
  int nbInit = (N + 255) >> 8;
  if ((int)blockIdx.x < nbInit) {
    int i = blockIdx.x * 256 + threadIdx.x;
    if (i < N) counts[i] = 0;
    return;
  }
  int bb = blockIdx.x - nbInit;                   // 0..191
  int b = bb >> 6;                                // which weight
  int t = (bb & 63) * 256 + threadIdx.x;          // 0..16383
  const float* W = (b == 0) ? Wa : (b == 1) ? Wb : Wc;
  unsigned short* wh = (b == 0) ? wha : (b == 1) ? whb : whc;
  unsigned short* wl = (b == 0) ? wla : (b == 1) ? wlb : wlc;
  int c = t >> 7, k = t & 127;
  float w = W[k * 128 + c];
  unsigned short hi = bf16_rtn(w);
  unsigned short lo = bf16_rtn(w - bf16_to_f(hi));
  wh[c * 128 + k] = hi;
  wl[c * 128 + k] = lo;
}

// ---------------------------------------------------------------------------
// Destination-sharded degree count. shard = blockIdx & 7 (XCD-aligned under
// the HW round-robin mapping); each shard scans all edges, counts only dst in
// its node range -> counts lines are single-XCD, no L2 coherence thrash.
// Each block covers 2048 edges (8 per thread, coalesced stride 256).
// ---------------------------------------------------------------------------
__global__ __launch_bounds__(256) void count_kernel(const int* __restrict__ ei32,
                                                    int* __restrict__ counts, int E, int N) {
  int shard = blockIdx.x & 7;
  int chunk = blockIdx.x >> 3;
  int ns = (N + 7) >> 3;
  int lo = shard * ns, hi = min(lo + ns, N);
  int base = chunk * 2048;
  int t = threadIdx.x;
  bool is64 = wave_is64(ei32, E, min(base + t, E - 1));
#pragma unroll
  for (int j = 0; j < 8; ++j) {
    int e = base + j * 256 + t;
    if (e >= E) break;
    int d = is64 ? ei32[2 * ((i64)E + e)] : ei32[(i64)E + e];
    if (d >= lo && d < hi) atomicAdd(&counts[d], 1);
  }
}

// ---------------------------------------------------------------------------
// Device-wide exclusive scan of counts (3 phases, 1024 elems per block).
// ---------------------------------------------------------------------------
__global__ __launch_bounds__(256) void psum_kernel(const int* __restrict__ counts,
                                                   int* __restrict__ bsum, int N) {
  int base = blockIdx.x * 1024 + threadIdx.x * 4;
  int s = 0;
#pragma unroll
  for (int j = 0; j < 4; ++j) {
    int i = base + j;
    if (i < N) s += counts[i];
  }
#pragma unroll
  for (int off = 32; off > 0; off >>= 1) s += __shfl_down(s, off);
  __shared__ int ws[4];
  int wid = threadIdx.x >> 6;
  if ((threadIdx.x & 63) == 0) ws[wid] = s;
  __syncthreads();
  if (threadIdx.x == 0) bsum[blockIdx.x] = ws[0] + ws[1] + ws[2] + ws[3];
}

__global__ __launch_bounds__(1024) void bscan_kernel(int* __restrict__ bsum, int nb,
                                                     int* __restrict__ offs_last, int E) {
  __shared__ int sh[1024];
  int tid = threadIdx.x;
  int v = (tid < nb) ? bsum[tid] : 0;
  sh[tid] = v;
  __syncthreads();
  for (int off = 1; off < 1024; off <<= 1) {
    int t = (tid >= off) ? sh[tid - off] : 0;
    __syncthreads();
    sh[tid] += t;
    __syncthreads();
  }
  if (tid < nb) bsum[tid] = sh[tid] - v;  // exclusive
  if (tid == 0) offs_last[0] = E;
}

__global__ __launch_bounds__(256) void scatter_kernel(
    const int* __restrict__ counts, const int* __restrict__ bsum,
    int* __restrict__ offs, int* __restrict__ cursor, float* __restrict__ dinv, int N) {
  __shared__ int wsum[4];
  int tid = threadIdx.x;
  int base = blockIdx.x * 1024 + tid * 4;
  int c[4];
  int s = 0;
#pragma unroll
  for (int j = 0; j < 4; ++j) {
    int i = base + j;
    c[j] = (i < N) ? counts[i] : 0;
    s += c[j];
  }
  int lane = tid & 63, wid = tid >> 6;
  int incl = s;
#pragma unroll
  for (int off = 1; off < 64; off <<= 1) {
    int t = __shfl_up(incl, off);
    if (lane >= off) incl += t;
  }
  if (lane == 63) wsum[wid] = incl;
  __syncthreads();
  int wo = 0;
  for (int wq = 0; wq < wid; ++wq) wo += wsum[wq];
  int excl = incl - s + wo + bsum[blockIdx.x];
#pragma unroll
  for (int j = 0; j < 4; ++j) {
    int i = base + j;
    if (i < N) {
      offs[i] = excl;
      cursor[i] = excl;
      dinv[i] = rsqrtf((float)c[j] + 1.0f);
      excl += c[j];
    }
  }
}

// ---------------------------------------------------------------------------
// Destination-sharded CSR fill (same sharding as count): cursor atomics and
// col writes stay in one XCD's L2 and evict densely.
// ---------------------------------------------------------------------------
__global__ __launch_bounds__(256) void fill_kernel(const int* __restrict__ ei32,
                                                   int* __restrict__ cursor,
                                                   int* __restrict__ col, int E, int N) {
  int shard = blockIdx.x & 7;
  int chunk = blockIdx.x >> 3;
  int ns = (N + 7) >> 3;
  int lo = shard * ns, hi = min(lo + ns, N);
  int base = chunk * 2048;
  int t = threadIdx.x;
  bool is64 = wave_is64(ei32, E, min(base + t, E - 1));
#pragma unroll
  for (int j = 0; j < 8; ++j) {
    int e = base + j * 256 + t;
    if (e >= E) break;
    int d = is64 ? ei32[2 * ((i64)E + e)] : ei32[(i64)E + e];
    if (d >= lo && d < hi) {
      int s = is64 ? ei32[2 * (i64)e] : ei32[e];
      int pos = atomicAdd(&cursor[d], 1);
      col[pos] = s;
    }
  }
}

// ---------------------------------------------------------------------------
// LDS-free split-bf16 MFMA GEMM: C[N,128] = A[N,128] @ W[128,128].
// A,W split hi+lo bf16, 3 MFMA passes (hh, lh, hl) -> ~fp32 accuracy.
// MODE 0: out = bf16( acc * dinv[row] )    MODE 1: out = relu(acc + bias[col])
// ---------------------------------------------------------------------------
template <int MODE>
__global__ __launch_bounds__(256, 4) void gemm_mfma(
    const float* __restrict__ A, const unsigned short* __restrict__ WhT,
    const unsigned short* __restrict__ WlT, const float* __restrict__ aux,
    void* __restrict__ outv, int N) {
  int tid = threadIdx.x;
  int wid = tid >> 6, lane = tid & 63;
  int lr = lane & 15, kg = (lane >> 4) * 8;
  int rowbase = blockIdx.x * 128 + wid * 32;

  f32x4 acc[2][8];
#pragma unroll
  for (int tr = 0; tr < 2; ++tr)
#pragma unroll
    for (int tc = 0; tc < 8; ++tc) acc[tr][tc] = (f32x4){0.f, 0.f, 0.f, 0.f};

  int r[2] = {rowbase + lr, rowbase + 16 + lr};

  for (int kc = 0; kc < 128; kc += 32) {
    int k0 = kc + kg;
    short8 afh[2], afl[2];
#pragma unroll
    for (int tr = 0; tr < 2; ++tr) {
      float4 va = make_float4(0.f, 0.f, 0.f, 0.f), vb = va;
      if (r[tr] < N) {
        const float* p = &A[(i64)r[tr] * 128 + k0];
        va = *reinterpret_cast<const float4*>(p);
        vb = *reinterpret_cast<const float4*>(p + 4);
      }
      float xs[8] = {va.x, va.y, va.z, va.w, vb.x, vb.y, vb.z, vb.w};
#pragma unroll
      for (int j = 0; j < 8; ++j) {
        unsigned short h = bf16_rtn(xs[j]);
        afh[tr][j] = (short)h;
        afl[tr][j] = (short)bf16_rtn(xs[j] - bf16_to_f(h));
      }
    }
#pragma unroll
    for (int tc = 0; tc < 8; ++tc) {
      int c = tc * 16 + lr;
      short8 bfh = *reinterpret_cast<const short8*>(&WhT[c * 128 + k0]);
      short8 bfl = *reinterpret_cast<const short8*>(&WlT[c * 128 + k0]);
#pragma unroll
      for (int tr = 0; tr < 2; ++tr) {
        acc[tr][tc] = __builtin_amdgcn_mfma_f32_16x16x32_bf16(afh[tr], bfh, acc[tr][tc], 0, 0, 0);
        acc[tr][tc] = __builtin_amdgcn_mfma_f32_16x16x32_bf16(afl[tr], bfh, acc[tr][tc], 0, 0, 0);
        acc[tr][tc] = __builtin_amdgcn_mfma_f32_16x16x32_bf16(afh[tr], bfl, acc[tr][tc], 0, 0, 0);
      }
    }
  }

  // epilogue (C/D layout: col = tc*16 + (lane&15), row = tr*16 + (lane>>4)*4 + reg)
  if (MODE == 0) {
    unsigned short* hb = (unsigned short*)outv;
#pragma unroll
    for (int tr = 0; tr < 2; ++tr) {
#pragma unroll
      for (int reg = 0; reg < 4; ++reg) {
        int row = rowbase + tr * 16 + (lane >> 4) * 4 + reg;
        if (row >= N) continue;
        float dv = aux[row];
#pragma unroll
        for (int tc = 0; tc < 8; ++tc) {
          int colg = tc * 16 + lr;
          hb[(i64)row * 128 + colg] = bf16_rtn(acc[tr][tc][reg] * dv);
        }
      }
    }
  } else {
    float* out = (float*)outv;
#pragma unroll
    for (int tr = 0; tr < 2; ++tr) {
#pragma unroll
      for (int reg = 0; reg < 4; ++reg) {
        int row = rowbase + tr * 16 + (lane >> 4) * 4 + reg;
        if (row >= N) continue;
#pragma unroll
        for (int tc = 0; tc < 8; ++tc) {
          int colg = tc * 16 + lr;
          out[(i64)row * 128 + colg] = fmaxf(acc[tr][tc][reg] + aux[colg], 0.f);
        }
      }
    }
  }
}

// ---------------------------------------------------------------------------
// Aggregation over bf16 H': out[v] = (relu?)( dinv[v]*(H'[v] + sum_s H'[s]) + b )
// Half-wave (32 lanes) per node, lane = 4 channels (8B us4), unroll 4 for MLP.
// ---------------------------------------------------------------------------
template <int RELU>
__global__ __launch_bounds__(256) void agg_bf16(
    const unsigned short* __restrict__ hb, const int* __restrict__ col,
    const int* __restrict__ offs, const float* __restrict__ dinv,
    const float* __restrict__ bias, float* __restrict__ out, int N) {
  i64 gt = (i64)blockIdx.x * blockDim.x + threadIdx.x;
  int gw = (int)(gt >> 6);
  int lane = threadIdx.x & 63;
  int v = gw * 2 + (lane >> 5);
  if (v >= N) return;
  int ch = (lane & 31) * 4;
  us4 sv = *reinterpret_cast<const us4*>(&hb[(i64)v * 128 + ch]);
  float a0 = bf16_to_f(sv[0]), a1 = bf16_to_f(sv[1]);
  float a2 = bf16_to_f(sv[2]), a3 = bf16_to_f(sv[3]);
  int beg = offs[v], end = offs[v + 1];
  int i = beg;
  for (; i + 3 < end; i += 4) {
    int s0 = col[i], s1 = col[i + 1], s2 = col[i + 2], s3 = col[i + 3];
    us4 u0 = *reinterpret_cast<const us4*>(&hb[(i64)s0 * 128 + ch]);
    us4 u1 = *reinterpret_cast<const us4*>(&hb[(i64)s1 * 128 + ch]);
    us4 u2 = *reinterpret_cast<const us4*>(&hb[(i64)s2 * 128 + ch]);
    us4 u3 = *reinterpret_cast<const us4*>(&hb[(i64)s3 * 128 + ch]);
    a0 += (bf16_to_f(u0[0]) + bf16_to_f(u1[0])) + (bf16_to_f(u2[0]) + bf16_to_f(u3[0]));
    a1 += (bf16_to_f(u0[1]) + bf16_to_f(u1[1])) + (bf16_to_f(u2[1]) + bf16_to_f(u3[1]));
    a2 += (bf16_to_f(u0[2]) + bf16_to_f(u1[2])) + (bf16_to_f(u2[2]) + bf16_to_f(u3[2]));
    a3 += (bf16_to_f(u0[3]) + bf16_to_f(u1[3])) + (bf16_to_f(u2[3]) + bf16_to_f(u3[3]));
  }
  for (; i < end; ++i) {
    int s0 = col[i];
    us4 u0 = *reinterpret_cast<const us4*>(&hb[(i64)s0 * 128 + ch]);
    a0 += bf16_to_f(u0[0]); a1 += bf16_to_f(u0[1]);
    a2 += bf16_to_f(u0[2]); a3 += bf16_to_f(u0[3]);
  }
  float dv = dinv[v];
  float4 b = *reinterpret_cast<const float4*>(&bias[ch]);
  float4 rr;
  rr.x = fmaf(a0, dv, b.x);
  rr.y = fmaf(a1, dv, b.y);
  rr.z = fmaf(a2, dv, b.z);
  rr.w = fmaf(a3, dv, b.w);
  if (RELU) {
    rr.x = fmaxf(rr.x, 0.f); rr.y = fmaxf(rr.y, 0.f);
    rr.z = fmaxf(rr.z, 0.f); rr.w = fmaxf(rr.w, 0.f);
  }
  *reinterpret_cast<float4*>(&out[(i64)v * 128 + ch]) = rr;
}

// ---------------------------------------------------------------------------
extern "C" void kernel_launch(void* const* d_in, const int* in_sizes, int n_in,
                              void* d_out, int out_size, void* d_ws, size_t ws_size,
                              hipStream_t stream) {
  const float* x  = (const float*)d_in[0];
  const int*   ei = (const int*)d_in[1];
  const float* W1 = (const float*)d_in[2];
  const float* b1 = (const float*)d_in[3];
  const float* W2 = (const float*)d_in[4];
  const float* b2 = (const float*)d_in[5];
  const float* Wd = (const float*)d_in[6];
  const float* bd = (const float*)d_in[7];
  int N = in_sizes[0] / 128;
  int E = in_sizes[1] / 2;
  float* out = (float*)d_out;

  // workspace layout
  char* w = (char*)d_ws;
  float*          z    = (float*)w;                        // N*128 fp32
  unsigned short* wh1  = (unsigned short*)(z + (i64)N * 128);
  unsigned short* wl1  = wh1 + 16384;
  unsigned short* wh2  = wl1 + 16384;
  unsigned short* wl2  = wh2 + 16384;
  unsigned short* whd  = wl2 + 16384;
  unsigned short* wld  = whd + 16384;
  int*   counts = (int*)(wld + 16384);
  int*   offs   = counts + N;                              // N+1
  int*   cursor = offs + N + 1;                            // N
  int*   col    = cursor + N;                              // E
  float* dinv   = (float*)(col + E);                       // N
  int*   bsum   = (int*)(dinv + N);                        // <=1024
  unsigned short* hb = (unsigned short*)d_out;  // bf16 H' scratch; overwritten by decoder

  int nb = (N + 1023) / 1024;
  int nbInit = (N + 255) / 256;
  int cb = (E + 2047) / 2048;

  init_split_kernel<<<nbInit + 192, 256, 0, stream>>>(counts, N,
      W1, wh1, wl1, W2, wh2, wl2, Wd, whd, wld);
  count_kernel<<<8 * cb, 256, 0, stream>>>(ei, counts, E, N);
  psum_kernel<<<nb, 256, 0, stream>>>(counts, bsum, N);
  bscan_kernel<<<1, 1024, 0, stream>>>(bsum, nb, offs + N, E);
  scatter_kernel<<<nb, 256, 0, stream>>>(counts, bsum, offs, cursor, dinv, N);
  fill_kernel<<<8 * cb, 256, 0, stream>>>(ei, cursor, col, E, N);

  int gblocks = (N + 127) / 128;
  i64 aggthreads = (i64)((N + 1) / 2) * 64;
  int ablocks = (int)((aggthreads + 255) / 256);

  // conv1: hb = bf16((x@W1)*dinv) ; z = relu(dinv*(hb_v + sum) + b1)
  gemm_mfma<0><<<gblocks, 256, 0, stream>>>(x, wh1, wl1, dinv, hb, N);
  agg_bf16<1><<<ablocks, 256, 0, stream>>>(hb, col, offs, dinv, b1, z, N);
  // conv2: hb = bf16((z@W2)*dinv) ; z = dinv*(hb_v + sum) + b2 (no relu)
  gemm_mfma<0><<<gblocks, 256, 0, stream>>>(z, wh2, wl2, dinv, hb, N);
  agg_bf16<0><<<ablocks, 256, 0, stream>>>(hb, col, offs, dinv, b2, z, N);
  // decoder: out = relu(z @ Wd + bd)
  gemm_mfma<1><<<gblocks, 256, 0, stream>>>(z, whd, wld, bd, out, N);
}